// Round 1
// baseline (2244.155 us; speedup 1.0000x reference)
//
#include <hip/hip_runtime.h>

#define USER_NUM 100000
#define ITEM_NUM 50000
#define N_ROWS   (USER_NUM + ITEM_NUM)   // 150000
#define EMB      64
#define NNZ      3000000
#define N_LAYERS 3
#define EPS      0.1f

// ---------------------------------------------------------------------------
// init: ego_A = concat(user, item); acc(=out) = same; ego_B = 0
// ---------------------------------------------------------------------------
__global__ __launch_bounds__(256) void init_kernel(
    const float* __restrict__ user, const float* __restrict__ item,
    float* __restrict__ egoA, float* __restrict__ acc, float* __restrict__ egoB)
{
    int i = blockIdx.x * blockDim.x + threadIdx.x;            // over N*EMB/4
    const int total4 = N_ROWS * EMB / 4;
    if (i >= total4) return;
    const int user4 = USER_NUM * EMB / 4;
    float4 v;
    if (i < user4) v = reinterpret_cast<const float4*>(user)[i];
    else           v = reinterpret_cast<const float4*>(item)[i - user4];
    reinterpret_cast<float4*>(egoA)[i] = v;
    reinterpret_cast<float4*>(acc)[i]  = v;
    reinterpret_cast<float4*>(egoB)[i] = make_float4(0.f, 0.f, 0.f, 0.f);
}

// ---------------------------------------------------------------------------
// SpMM (COO): one 64-lane wave per edge; lane d handles dim d.
// y[rows[e]][d] += vals[e] * x[cols[e]][d]   via global atomicAdd
// ---------------------------------------------------------------------------
__global__ __launch_bounds__(256) void spmm_kernel(
    const float* __restrict__ vals, const int* __restrict__ rows,
    const int* __restrict__ cols, const float* __restrict__ x,
    float* __restrict__ y)
{
    int e = blockIdx.x * 4 + (threadIdx.x >> 6);
    if (e >= NNZ) return;
    int d = threadIdx.x & 63;
    float v = vals[e];
    int r = rows[e];
    int c = cols[e];
    float xv = x[(size_t)c * EMB + d];
    atomicAdd(&y[(size_t)r * EMB + d], v * xv);
}

// ---------------------------------------------------------------------------
// perturb + accumulate (+ zero the other buffer for next layer):
//   nrm  = noise_row / max(||noise_row||, 1e-12)
//   ego += sign(ego) * nrm * EPS
//   acc += ego            (acc lives in d_out)
//   last layer: acc *= 0.25 (the /(L+1) average), skip ego/zero writes
// one 64-lane wave per row
// ---------------------------------------------------------------------------
__global__ __launch_bounds__(256) void perturb_kernel(
    float* __restrict__ ego, const float* __restrict__ noise,
    float* __restrict__ acc, float* __restrict__ zero_buf, int last)
{
    int row = blockIdx.x * 4 + (threadIdx.x >> 6);
    if (row >= N_ROWS) return;
    int d = threadIdx.x & 63;
    int idx = row * EMB + d;

    float nv = noise[idx];
    float s = nv * nv;
    #pragma unroll
    for (int off = 32; off; off >>= 1) s += __shfl_xor(s, off, 64);
    float nrm = nv / fmaxf(sqrtf(s), 1e-12f);

    float e = ego[idx];
    float sg = (e > 0.f) ? 1.f : ((e < 0.f) ? -1.f : 0.f);
    float e2 = e + sg * nrm * EPS;

    float a = acc[idx] + e2;
    if (last) {
        acc[idx] = a * 0.25f;       // /(N_LAYERS+1)
    } else {
        acc[idx] = a;
        ego[idx] = e2;              // becomes next layer's input
        zero_buf[idx] = 0.f;        // next layer's atomic target
    }
}

// ---------------------------------------------------------------------------
extern "C" void kernel_launch(void* const* d_in, const int* in_sizes, int n_in,
                              void* d_out, int out_size, void* d_ws, size_t ws_size,
                              hipStream_t stream)
{
    const float* user  = (const float*)d_in[0];
    const float* item  = (const float*)d_in[1];
    const float* vals  = (const float*)d_in[2];
    const float* noise = (const float*)d_in[3];
    const int*   rows  = (const int*)d_in[4];
    const int*   cols  = (const int*)d_in[5];
    float* out = (float*)d_out;

    const size_t nelem = (size_t)N_ROWS * EMB;
    float* bufA = (float*)d_ws;
    float* bufB = bufA + nelem;

    // init
    {
        int total4 = N_ROWS * EMB / 4;
        int blocks = (total4 + 255) / 256;
        init_kernel<<<blocks, 256, 0, stream>>>(user, item, bufA, out, bufB);
    }

    float* cur = bufA;
    float* nxt = bufB;
    const int spmm_blocks = (NNZ + 3) / 4;
    const int row_blocks  = (N_ROWS + 3) / 4;

    for (int k = 0; k < N_LAYERS; ++k) {
        spmm_kernel<<<spmm_blocks, 256, 0, stream>>>(vals, rows, cols, cur, nxt);
        int last = (k == N_LAYERS - 1);
        perturb_kernel<<<row_blocks, 256, 0, stream>>>(
            nxt, noise + (size_t)k * nelem, out, cur, last);
        float* t = cur; cur = nxt; nxt = t;
    }
}

// Round 2
// 1175.635 us; speedup vs baseline: 1.9089x; 1.9089x over previous
//
#include <hip/hip_runtime.h>

#define USER_NUM 100000
#define ITEM_NUM 50000
#define N_ROWS   (USER_NUM + ITEM_NUM)   // 150000
#define EMB      64
#define NNZ      3000000
#define N_LAYERS 3
#define EPS      0.1f

#define SCAN_BS  256
#define NB       ((N_ROWS + SCAN_BS - 1) / SCAN_BS)   // 586 blocks

// ---------------------------------------------------------------------------
// init: ego_A = concat(user, item); acc(=out) = same
// ---------------------------------------------------------------------------
__global__ __launch_bounds__(256) void init_kernel(
    const float* __restrict__ user, const float* __restrict__ item,
    float* __restrict__ egoA, float* __restrict__ acc)
{
    int i = blockIdx.x * blockDim.x + threadIdx.x;            // over N*EMB/4
    const int total4 = N_ROWS * EMB / 4;
    if (i >= total4) return;
    const int user4 = USER_NUM * EMB / 4;
    float4 v;
    if (i < user4) v = reinterpret_cast<const float4*>(user)[i];
    else           v = reinterpret_cast<const float4*>(item)[i - user4];
    reinterpret_cast<float4*>(egoA)[i] = v;
    reinterpret_cast<float4*>(acc)[i]  = v;
}

// ---------------------------------------------------------------------------
// counting sort, phase 1: histogram of row indices
// ---------------------------------------------------------------------------
__global__ __launch_bounds__(256) void count_kernel(
    const int* __restrict__ rows, int* __restrict__ cnt)
{
    int e = blockIdx.x * blockDim.x + threadIdx.x;
    if (e >= NNZ) return;
    atomicAdd(&cnt[rows[e]], 1);
}

// ---------------------------------------------------------------------------
// scan A: per-block exclusive scan of cnt -> cursor, block sums -> blk
// ---------------------------------------------------------------------------
__global__ __launch_bounds__(SCAN_BS) void scanA_kernel(
    const int* __restrict__ cnt, int* __restrict__ cursor, int* __restrict__ blk)
{
    __shared__ int tmp[SCAN_BS];
    int t = threadIdx.x;
    int i = blockIdx.x * SCAN_BS + t;
    int v = (i < N_ROWS) ? cnt[i] : 0;
    tmp[t] = v;
    __syncthreads();
    for (int off = 1; off < SCAN_BS; off <<= 1) {
        int x = (t >= off) ? tmp[t - off] : 0;
        __syncthreads();
        tmp[t] += x;
        __syncthreads();
    }
    if (i < N_ROWS) cursor[i] = tmp[t] - v;      // exclusive
    if (t == SCAN_BS - 1) blk[blockIdx.x] = tmp[t];
}

// ---------------------------------------------------------------------------
// scan B: single block scans the NB block sums (exclusive)
// ---------------------------------------------------------------------------
__global__ __launch_bounds__(1024) void scanB_kernel(int* __restrict__ blk)
{
    __shared__ int tmp[1024];
    int t = threadIdx.x;
    int v = (t < NB) ? blk[t] : 0;
    tmp[t] = v;
    __syncthreads();
    for (int off = 1; off < 1024; off <<= 1) {
        int x = (t >= off) ? tmp[t - off] : 0;
        __syncthreads();
        tmp[t] += x;
        __syncthreads();
    }
    if (t < NB) blk[t] = tmp[t] - v;             // exclusive
}

// ---------------------------------------------------------------------------
// scan C: add block offsets -> cursor holds each row's START
// ---------------------------------------------------------------------------
__global__ __launch_bounds__(SCAN_BS) void scanC_kernel(
    int* __restrict__ cursor, const int* __restrict__ blk)
{
    int i = blockIdx.x * SCAN_BS + threadIdx.x;
    if (i >= N_ROWS) return;
    cursor[i] += blk[blockIdx.x];
}

// ---------------------------------------------------------------------------
// counting sort, phase 2: scatter {val, col} pairs into row-sorted order.
// cursor[row] advances from start to end; afterwards cursor[row] == row end.
// ---------------------------------------------------------------------------
__global__ __launch_bounds__(256) void scatter_kernel(
    const int* __restrict__ rows, const int* __restrict__ cols,
    const float* __restrict__ vals, int* __restrict__ cursor,
    float2* __restrict__ sorted)
{
    int e = blockIdx.x * blockDim.x + threadIdx.x;
    if (e >= NNZ) return;
    int r = rows[e];
    int pos = atomicAdd(&cursor[r], 1);
    sorted[pos] = make_float2(vals[e], __int_as_float(cols[e]));
}

// ---------------------------------------------------------------------------
// fused layer: CSR SpMM (wave per row, no atomics) + perturb + acc update.
//   start = cursor[row] - cnt[row]  (cursor holds END after scatter)
//   ego = spmm(x); ego += sign(ego)*normalize(noise_row)*EPS
//   acc += ego; last layer: acc *= 1/(N_LAYERS+1)
// ---------------------------------------------------------------------------
__global__ __launch_bounds__(256) void layer_kernel(
    const float2* __restrict__ sorted, const int* __restrict__ endp,
    const int* __restrict__ cnt, const float* __restrict__ x,
    float* __restrict__ ego_out, const float* __restrict__ noise,
    float* __restrict__ acc, int last)
{
    int row = blockIdx.x * 4 + (threadIdx.x >> 6);
    if (row >= N_ROWS) return;
    int lane = threadIdx.x & 63;

    int end = endp[row];
    int deg = cnt[row];
    int start = end - deg;

    float accv = 0.f;
    for (int base = 0; base < deg; base += 64) {
        int m = min(deg - base, 64);
        float2 ed = (lane < m) ? sorted[start + base + lane]
                               : make_float2(0.f, 0.f);
        #pragma unroll 4
        for (int e = 0; e < m; ++e) {
            float v = __shfl(ed.x, e, 64);
            int   c = __shfl(__float_as_int(ed.y), e, 64);
            accv = fmaf(v, x[(size_t)c * EMB + lane], accv);
        }
    }

    int idx = row * EMB + lane;
    float nv = noise[idx];
    float s = nv * nv;
    #pragma unroll
    for (int off = 32; off; off >>= 1) s += __shfl_xor(s, off, 64);
    float nrm = nv / fmaxf(sqrtf(s), 1e-12f);

    float sg = (accv > 0.f) ? 1.f : ((accv < 0.f) ? -1.f : 0.f);
    float e2 = accv + sg * nrm * EPS;

    float a = acc[idx] + e2;
    if (last) {
        acc[idx] = a * 0.25f;        // /(N_LAYERS+1)
    } else {
        acc[idx] = a;
        ego_out[idx] = e2;           // next layer's input
    }
}

// ---------------------------------------------------------------------------
extern "C" void kernel_launch(void* const* d_in, const int* in_sizes, int n_in,
                              void* d_out, int out_size, void* d_ws, size_t ws_size,
                              hipStream_t stream)
{
    const float* user  = (const float*)d_in[0];
    const float* item  = (const float*)d_in[1];
    const float* vals  = (const float*)d_in[2];
    const float* noise = (const float*)d_in[3];
    const int*   rows  = (const int*)d_in[4];
    const int*   cols  = (const int*)d_in[5];
    float* out = (float*)d_out;

    const size_t nelem = (size_t)N_ROWS * EMB;

    // workspace layout
    float*  bufA   = (float*)d_ws;                       // N*EMB
    float*  bufB   = bufA + nelem;                       // N*EMB
    float2* sorted = (float2*)(bufB + nelem);            // NNZ float2
    int*    cnt    = (int*)(sorted + NNZ);               // N_ROWS
    int*    cursor = cnt + N_ROWS;                       // N_ROWS
    int*    blk    = cursor + N_ROWS;                    // NB

    // zero the histogram (ws is poisoned every call)
    hipMemsetAsync(cnt, 0, N_ROWS * sizeof(int), stream);

    // init: ego_A = acc = concat(user, item)
    {
        int total4 = N_ROWS * EMB / 4;
        init_kernel<<<(total4 + 255) / 256, 256, 0, stream>>>(user, item, bufA, out);
    }

    // counting sort: edges grouped by destination row
    const int eb = (NNZ + 255) / 256;
    count_kernel<<<eb, 256, 0, stream>>>(rows, cnt);
    scanA_kernel<<<NB, SCAN_BS, 0, stream>>>(cnt, cursor, blk);
    scanB_kernel<<<1, 1024, 0, stream>>>(blk);
    scanC_kernel<<<NB, SCAN_BS, 0, stream>>>(cursor, blk);
    scatter_kernel<<<eb, 256, 0, stream>>>(rows, cols, vals, cursor, sorted);

    // 3 fused layers, ping-pong ego buffers
    float* cur = bufA;
    float* nxt = bufB;
    const int row_blocks = (N_ROWS + 3) / 4;
    for (int k = 0; k < N_LAYERS; ++k) {
        int last = (k == N_LAYERS - 1);
        layer_kernel<<<row_blocks, 256, 0, stream>>>(
            sorted, cursor, cnt, cur, nxt,
            noise + (size_t)k * nelem, out, last);
        float* t = cur; cur = nxt; nxt = t;
    }
}

// Round 3
// 913.426 us; speedup vs baseline: 2.4569x; 1.2871x over previous
//
#include <hip/hip_runtime.h>

#define USER_NUM 100000
#define ITEM_NUM 50000
#define N_ROWS   (USER_NUM + ITEM_NUM)   // 150000
#define EMB      64
#define NNZ      3000000
#define N_LAYERS 3
#define EPS      0.1f

#define RPB      512                               // rows per bucket (pow2)
#define RPB_LOG  9
#define NBUCK    ((N_ROWS + RPB - 1) / RPB)        // 293
#define NBP      512                               // padded bucket count (pow2)
#define P1_CH    4096                              // edges per pass1/count block
#define P1_T     512
#define P1_EPT   (P1_CH / P1_T)                    // 8
#define P1_BLOCKS ((NNZ + P1_CH - 1) / P1_CH)      // 733

// ---------------------------------------------------------------------------
// init: ego_A = concat(user, item); acc(=out) = same
// ---------------------------------------------------------------------------
__global__ __launch_bounds__(256) void init_kernel(
    const float* __restrict__ user, const float* __restrict__ item,
    float* __restrict__ egoA, float* __restrict__ acc)
{
    int i = blockIdx.x * blockDim.x + threadIdx.x;            // over N*EMB/4
    const int total4 = N_ROWS * EMB / 4;
    if (i >= total4) return;
    const int user4 = USER_NUM * EMB / 4;
    float4 v;
    if (i < user4) v = reinterpret_cast<const float4*>(user)[i];
    else           v = reinterpret_cast<const float4*>(item)[i - user4];
    reinterpret_cast<float4*>(egoA)[i] = v;
    reinterpret_cast<float4*>(acc)[i]  = v;
}

// ---------------------------------------------------------------------------
// bucket histogram: LDS-aggregated counts of edges per 512-row bucket
// ---------------------------------------------------------------------------
__global__ __launch_bounds__(256) void bucket_count_kernel(
    const int* __restrict__ rows, int* __restrict__ gbcnt)
{
    __shared__ int h[NBP];
    for (int i = threadIdx.x; i < NBP; i += 256) h[i] = 0;
    __syncthreads();
    size_t base = (size_t)blockIdx.x * P1_CH;
    #pragma unroll
    for (int k = 0; k < 16; ++k) {
        size_t e = base + k * 256 + threadIdx.x;
        if (e < NNZ) atomicAdd(&h[rows[e] >> RPB_LOG], 1);
    }
    __syncthreads();
    for (int i = threadIdx.x; i < NBUCK; i += 256)
        if (h[i]) atomicAdd(&gbcnt[i], h[i]);
}

// ---------------------------------------------------------------------------
// bucket scan: exclusive scan of the 293 bucket counts (one block)
// ---------------------------------------------------------------------------
__global__ __launch_bounds__(NBP) void bucket_scan_kernel(
    const int* __restrict__ gbcnt, int* __restrict__ gbstart, int* __restrict__ gcur)
{
    __shared__ int tmp[NBP];
    int t = threadIdx.x;
    int v = (t < NBUCK) ? gbcnt[t] : 0;
    tmp[t] = v;
    __syncthreads();
    for (int off = 1; off < NBP; off <<= 1) {
        int x = (t >= off) ? tmp[t - off] : 0;
        __syncthreads();
        tmp[t] += x;
        __syncthreads();
    }
    if (t < NBUCK) { int s = tmp[t] - v; gbstart[t] = s; gcur[t] = s; }
}

// ---------------------------------------------------------------------------
// pass1: LDS-binned scatter into bucket regions; writes become ~112B runs.
// payload: uint2{ val_bits, (col<<9) | (row&511) }
// ---------------------------------------------------------------------------
__global__ __launch_bounds__(P1_T) void pass1_kernel(
    const int* __restrict__ rows, const int* __restrict__ cols,
    const float* __restrict__ vals, int* __restrict__ gcur,
    uint2* __restrict__ p1out)
{
    __shared__ int cnt[NBP];
    __shared__ int scn[NBP];
    __shared__ int gb[NBP];
    __shared__ int cur[NBP];
    __shared__ uint2 stage[P1_CH];
    __shared__ unsigned short sbid[P1_CH];

    int t = threadIdx.x;
    size_t base = (size_t)blockIdx.x * P1_CH;
    int M = (int)min((long long)P1_CH, (long long)NNZ - (long long)base);

    cnt[t] = 0;                                   // NBP == P1_T
    __syncthreads();
    #pragma unroll
    for (int k = 0; k < P1_EPT; ++k) {
        int i = k * P1_T + t;
        if (i < M) atomicAdd(&cnt[rows[base + i] >> RPB_LOG], 1);
    }
    __syncthreads();
    scn[t] = cnt[t];                              // exclusive scan
    __syncthreads();
    for (int off = 1; off < NBP; off <<= 1) {
        int x = (t >= off) ? scn[t - off] : 0;
        __syncthreads();
        scn[t] += x;
        __syncthreads();
    }
    scn[t] -= cnt[t];
    if (t < NBUCK) gb[t] = atomicAdd(&gcur[t], cnt[t]);   // reserve chunk
    cur[t] = scn[t];
    __syncthreads();
    #pragma unroll
    for (int k = 0; k < P1_EPT; ++k) {            // stage grouped by bucket
        int i = k * P1_T + t;
        if (i < M) {
            size_t e = base + i;
            int r = rows[e];
            int b = r >> RPB_LOG;
            int slot = atomicAdd(&cur[b], 1);
            unsigned int packed = ((unsigned int)cols[e] << RPB_LOG) |
                                  (unsigned int)(r & (RPB - 1));
            stage[slot] = make_uint2(__float_as_uint(vals[e]), packed);
            sbid[slot] = (unsigned short)b;
        }
    }
    __syncthreads();
    for (int i = t; i < M; i += P1_T) {           // coalesced-run flush
        int b = sbid[i];
        p1out[(size_t)gb[b] + (i - scn[b])] = stage[i];
    }
}

// ---------------------------------------------------------------------------
// pass2: one block per bucket; exact row placement inside the block-private
// L2-resident window; also emits rowptr for the layer kernel.
// ---------------------------------------------------------------------------
__global__ __launch_bounds__(NBP) void pass2_kernel(
    const uint2* __restrict__ p1out, const int* __restrict__ gbcnt,
    const int* __restrict__ gbstart, int* __restrict__ rowptr,
    float2* __restrict__ sorted)
{
    __shared__ int h[RPB];
    __shared__ int sc[RPB];
    __shared__ int rcur[RPB];
    int t = threadIdx.x;                          // 512 == RPB
    int b = blockIdx.x;
    int s0 = gbstart[b];
    int nb = gbcnt[b];

    h[t] = 0;
    __syncthreads();
    for (int i = t; i < nb; i += NBP) {
        unsigned int rl = p1out[(size_t)s0 + i].y & (RPB - 1);
        atomicAdd(&h[rl], 1);
    }
    __syncthreads();
    sc[t] = h[t];
    __syncthreads();
    for (int off = 1; off < RPB; off <<= 1) {
        int x = (t >= off) ? sc[t - off] : 0;
        __syncthreads();
        sc[t] += x;
        __syncthreads();
    }
    sc[t] -= h[t];
    int r = b * RPB + t;
    int rs = s0 + sc[t];
    if (r < N_ROWS) rowptr[r] = rs;
    rcur[t] = rs;
    __syncthreads();
    for (int i = t; i < nb; i += NBP) {
        uint2 q = p1out[(size_t)s0 + i];
        int rl = q.y & (RPB - 1);
        int c  = (int)(q.y >> RPB_LOG);
        int dst = atomicAdd(&rcur[rl], 1);
        sorted[dst] = make_float2(__uint_as_float(q.x), __int_as_float(c));
    }
    if (b == 0 && t == 0) rowptr[N_ROWS] = NNZ;
}

// ---------------------------------------------------------------------------
// fused layer: CSR SpMM (wave per row, no atomics) + perturb + acc update
// ---------------------------------------------------------------------------
__global__ __launch_bounds__(256) void layer_kernel(
    const float2* __restrict__ sorted, const int* __restrict__ rowptr,
    const float* __restrict__ x, float* __restrict__ ego_out,
    const float* __restrict__ noise, float* __restrict__ acc, int last)
{
    int row = blockIdx.x * 4 + (threadIdx.x >> 6);
    if (row >= N_ROWS) return;
    int lane = threadIdx.x & 63;

    int start = rowptr[row];
    int deg   = rowptr[row + 1] - start;

    float accv = 0.f;
    for (int base = 0; base < deg; base += 64) {
        int m = min(deg - base, 64);
        float2 ed = (lane < m) ? sorted[start + base + lane]
                               : make_float2(0.f, 0.f);
        #pragma unroll 8
        for (int e = 0; e < m; ++e) {
            float v = __shfl(ed.x, e, 64);
            int   c = __shfl(__float_as_int(ed.y), e, 64);
            accv = fmaf(v, x[(size_t)c * EMB + lane], accv);
        }
    }

    int idx = row * EMB + lane;
    float nv = noise[idx];
    float s = nv * nv;
    #pragma unroll
    for (int off = 32; off; off >>= 1) s += __shfl_xor(s, off, 64);
    float nrm = nv / fmaxf(sqrtf(s), 1e-12f);

    float sg = (accv > 0.f) ? 1.f : ((accv < 0.f) ? -1.f : 0.f);
    float e2 = accv + sg * nrm * EPS;

    float a = acc[idx] + e2;
    if (last) {
        acc[idx] = a * 0.25f;        // /(N_LAYERS+1)
    } else {
        acc[idx] = a;
        ego_out[idx] = e2;           // next layer's input
    }
}

// ---------------------------------------------------------------------------
// fallback path (round-1 atomic SpMM) if ws_size is too small for the sort
// ---------------------------------------------------------------------------
__global__ __launch_bounds__(256) void spmm_atomic_kernel(
    const float* __restrict__ vals, const int* __restrict__ rows,
    const int* __restrict__ cols, const float* __restrict__ x,
    float* __restrict__ y)
{
    int e = blockIdx.x * 4 + (threadIdx.x >> 6);
    if (e >= NNZ) return;
    int d = threadIdx.x & 63;
    atomicAdd(&y[(size_t)rows[e] * EMB + d], vals[e] * x[(size_t)cols[e] * EMB + d]);
}

__global__ __launch_bounds__(256) void perturb_atomic_kernel(
    float* __restrict__ ego, const float* __restrict__ noise,
    float* __restrict__ acc, float* __restrict__ zero_buf, int last)
{
    int row = blockIdx.x * 4 + (threadIdx.x >> 6);
    if (row >= N_ROWS) return;
    int d = threadIdx.x & 63;
    int idx = row * EMB + d;
    float nv = noise[idx];
    float s = nv * nv;
    #pragma unroll
    for (int off = 32; off; off >>= 1) s += __shfl_xor(s, off, 64);
    float nrm = nv / fmaxf(sqrtf(s), 1e-12f);
    float e = ego[idx];
    float sg = (e > 0.f) ? 1.f : ((e < 0.f) ? -1.f : 0.f);
    float e2 = e + sg * nrm * EPS;
    float a = acc[idx] + e2;
    if (last) acc[idx] = a * 0.25f;
    else { acc[idx] = a; ego[idx] = e2; zero_buf[idx] = 0.f; }
}

// ---------------------------------------------------------------------------
extern "C" void kernel_launch(void* const* d_in, const int* in_sizes, int n_in,
                              void* d_out, int out_size, void* d_ws, size_t ws_size,
                              hipStream_t stream)
{
    const float* user  = (const float*)d_in[0];
    const float* item  = (const float*)d_in[1];
    const float* vals  = (const float*)d_in[2];
    const float* noise = (const float*)d_in[3];
    const int*   rows  = (const int*)d_in[4];
    const int*   cols  = (const int*)d_in[5];
    float* out = (float*)d_out;

    const size_t nelem = (size_t)N_ROWS * EMB;

    // workspace layout
    float*  bufA    = (float*)d_ws;                      // N*EMB
    float*  bufB    = bufA + nelem;                      // N*EMB
    float2* sorted  = (float2*)(bufB + nelem);           // NNZ float2
    int*    rowptr  = (int*)(sorted + NNZ);              // N_ROWS + 1
    int*    gbcnt   = rowptr + (N_ROWS + 1);             // NBP
    int*    gbstart = gbcnt + NBP;                       // NBP
    int*    gcur    = gbstart + NBP;                     // NBP
    uint2*  p1out   = (uint2*)bufB;                      // overlays bufB (dead until layer1)

    const size_t need = (2 * nelem + 2 * NNZ) * 4 + (N_ROWS + 1 + 3 * NBP) * 4;
    const int row_blocks = (N_ROWS + 3) / 4;
    const int total4 = N_ROWS * EMB / 4;

    if (ws_size >= need) {
        // ---- sorted CSR path ----
        hipMemsetAsync(gbcnt, 0, NBP * sizeof(int), stream);
        init_kernel<<<(total4 + 255) / 256, 256, 0, stream>>>(user, item, bufA, out);

        bucket_count_kernel<<<P1_BLOCKS, 256, 0, stream>>>(rows, gbcnt);
        bucket_scan_kernel<<<1, NBP, 0, stream>>>(gbcnt, gbstart, gcur);
        pass1_kernel<<<P1_BLOCKS, P1_T, 0, stream>>>(rows, cols, vals, gcur, p1out);
        pass2_kernel<<<NBUCK, NBP, 0, stream>>>(p1out, gbcnt, gbstart, rowptr, sorted);

        float* cur = bufA;
        float* nxt = bufB;
        for (int k = 0; k < N_LAYERS; ++k) {
            int last = (k == N_LAYERS - 1);
            layer_kernel<<<row_blocks, 256, 0, stream>>>(
                sorted, rowptr, cur, nxt, noise + (size_t)k * nelem, out, last);
            float* t = cur; cur = nxt; nxt = t;
        }
    } else {
        // ---- fallback: atomic SpMM path ----
        hipMemsetAsync(bufB, 0, nelem * sizeof(float), stream);
        init_kernel<<<(total4 + 255) / 256, 256, 0, stream>>>(user, item, bufA, out);
        float* cur = bufA;
        float* nxt = bufB;
        const int spmm_blocks = (NNZ + 3) / 4;
        for (int k = 0; k < N_LAYERS; ++k) {
            spmm_atomic_kernel<<<spmm_blocks, 256, 0, stream>>>(vals, rows, cols, cur, nxt);
            int last = (k == N_LAYERS - 1);
            perturb_atomic_kernel<<<row_blocks, 256, 0, stream>>>(
                nxt, noise + (size_t)k * nelem, out, cur, last);
            float* t = cur; cur = nxt; nxt = t;
        }
    }
}

// Round 4
// 658.065 us; speedup vs baseline: 3.4102x; 1.3880x over previous
//
#include <hip/hip_runtime.h>

#define USER_NUM 100000
#define ITEM_NUM 50000
#define N_ROWS   (USER_NUM + ITEM_NUM)   // 150000
#define EMB      64
#define NNZ      3000000
#define N_LAYERS 3
#define EPS      0.1f

#define RPB      512                               // rows per bucket (pow2)
#define RPB_LOG  9
#define NBUCK    ((N_ROWS + RPB - 1) / RPB)        // 293
#define NBP      512                               // padded bucket count (pow2)
#define P1_CH    4096                               // edges per pass1/count block
#define P1_T     512
#define P1_EPT   (P1_CH / P1_T)                    // 8
#define P1_BLOCKS ((NNZ + P1_CH - 1) / P1_CH)      // 733

// ---------------------------------------------------------------------------
// init (fallback path only): ego_A = concat(user, item); acc(=out) = same
// ---------------------------------------------------------------------------
__global__ __launch_bounds__(256) void init_kernel(
    const float* __restrict__ user, const float* __restrict__ item,
    float* __restrict__ egoA, float* __restrict__ acc)
{
    int i = blockIdx.x * blockDim.x + threadIdx.x;            // over N*EMB/4
    const int total4 = N_ROWS * EMB / 4;
    if (i >= total4) return;
    const int user4 = USER_NUM * EMB / 4;
    float4 v;
    if (i < user4) v = reinterpret_cast<const float4*>(user)[i];
    else           v = reinterpret_cast<const float4*>(item)[i - user4];
    reinterpret_cast<float4*>(egoA)[i] = v;
    reinterpret_cast<float4*>(acc)[i]  = v;
}

// ---------------------------------------------------------------------------
// bucket histogram: LDS-aggregated counts of edges per 512-row bucket
// ---------------------------------------------------------------------------
__global__ __launch_bounds__(256) void bucket_count_kernel(
    const int* __restrict__ rows, int* __restrict__ gbcnt)
{
    __shared__ int h[NBP];
    for (int i = threadIdx.x; i < NBP; i += 256) h[i] = 0;
    __syncthreads();
    size_t base = (size_t)blockIdx.x * P1_CH;
    #pragma unroll
    for (int k = 0; k < 16; ++k) {
        size_t e = base + k * 256 + threadIdx.x;
        if (e < NNZ) atomicAdd(&h[rows[e] >> RPB_LOG], 1);
    }
    __syncthreads();
    for (int i = threadIdx.x; i < NBUCK; i += 256)
        if (h[i]) atomicAdd(&gbcnt[i], h[i]);
}

// ---------------------------------------------------------------------------
// bucket scan: exclusive scan of the 293 bucket counts (one block)
// ---------------------------------------------------------------------------
__global__ __launch_bounds__(NBP) void bucket_scan_kernel(
    const int* __restrict__ gbcnt, int* __restrict__ gbstart, int* __restrict__ gcur)
{
    __shared__ int tmp[NBP];
    int t = threadIdx.x;
    int v = (t < NBUCK) ? gbcnt[t] : 0;
    tmp[t] = v;
    __syncthreads();
    for (int off = 1; off < NBP; off <<= 1) {
        int x = (t >= off) ? tmp[t - off] : 0;
        __syncthreads();
        tmp[t] += x;
        __syncthreads();
    }
    if (t < NBUCK) { int s = tmp[t] - v; gbstart[t] = s; gcur[t] = s; }
}

// ---------------------------------------------------------------------------
// pass1: LDS-binned scatter into bucket regions; writes become ~112B runs.
// payload: uint2{ val_bits, (col<<9) | (row&511) }
// ---------------------------------------------------------------------------
__global__ __launch_bounds__(P1_T) void pass1_kernel(
    const int* __restrict__ rows, const int* __restrict__ cols,
    const float* __restrict__ vals, int* __restrict__ gcur,
    uint2* __restrict__ p1out)
{
    __shared__ int cnt[NBP];
    __shared__ int scn[NBP];
    __shared__ int gb[NBP];
    __shared__ int cur[NBP];
    __shared__ uint2 stage[P1_CH];
    __shared__ unsigned short sbid[P1_CH];

    int t = threadIdx.x;
    size_t base = (size_t)blockIdx.x * P1_CH;
    int M = (int)min((long long)P1_CH, (long long)NNZ - (long long)base);

    cnt[t] = 0;                                   // NBP == P1_T
    __syncthreads();
    #pragma unroll
    for (int k = 0; k < P1_EPT; ++k) {
        int i = k * P1_T + t;
        if (i < M) atomicAdd(&cnt[rows[base + i] >> RPB_LOG], 1);
    }
    __syncthreads();
    scn[t] = cnt[t];                              // exclusive scan
    __syncthreads();
    for (int off = 1; off < NBP; off <<= 1) {
        int x = (t >= off) ? scn[t - off] : 0;
        __syncthreads();
        scn[t] += x;
        __syncthreads();
    }
    scn[t] -= cnt[t];
    if (t < NBUCK) gb[t] = atomicAdd(&gcur[t], cnt[t]);   // reserve chunk
    cur[t] = scn[t];
    __syncthreads();
    #pragma unroll
    for (int k = 0; k < P1_EPT; ++k) {            // stage grouped by bucket
        int i = k * P1_T + t;
        if (i < M) {
            size_t e = base + i;
            int r = rows[e];
            int b = r >> RPB_LOG;
            int slot = atomicAdd(&cur[b], 1);
            unsigned int packed = ((unsigned int)cols[e] << RPB_LOG) |
                                  (unsigned int)(r & (RPB - 1));
            stage[slot] = make_uint2(__float_as_uint(vals[e]), packed);
            sbid[slot] = (unsigned short)b;
        }
    }
    __syncthreads();
    for (int i = t; i < M; i += P1_T) {           // coalesced-run flush
        int b = sbid[i];
        p1out[(size_t)gb[b] + (i - scn[b])] = stage[i];
    }
}

// ---------------------------------------------------------------------------
// pass2: one block per bucket; exact row placement inside the block-private
// L2-resident window; also emits rowptr for the layer kernel.
// ---------------------------------------------------------------------------
__global__ __launch_bounds__(NBP) void pass2_kernel(
    const uint2* __restrict__ p1out, const int* __restrict__ gbcnt,
    const int* __restrict__ gbstart, int* __restrict__ rowptr,
    float2* __restrict__ sorted)
{
    __shared__ int h[RPB];
    __shared__ int sc[RPB];
    __shared__ int rcur[RPB];
    int t = threadIdx.x;                          // 512 == RPB
    int b = blockIdx.x;
    int s0 = gbstart[b];
    int nb = gbcnt[b];

    h[t] = 0;
    __syncthreads();
    for (int i = t; i < nb; i += NBP) {
        unsigned int rl = p1out[(size_t)s0 + i].y & (RPB - 1);
        atomicAdd(&h[rl], 1);
    }
    __syncthreads();
    sc[t] = h[t];
    __syncthreads();
    for (int off = 1; off < RPB; off <<= 1) {
        int x = (t >= off) ? sc[t - off] : 0;
        __syncthreads();
        sc[t] += x;
        __syncthreads();
    }
    sc[t] -= h[t];
    int r = b * RPB + t;
    int rs = s0 + sc[t];
    if (r < N_ROWS) rowptr[r] = rs;
    rcur[t] = rs;
    __syncthreads();
    for (int i = t; i < nb; i += NBP) {
        uint2 q = p1out[(size_t)s0 + i];
        int rl = q.y & (RPB - 1);
        int c  = (int)(q.y >> RPB_LOG);
        int dst = atomicAdd(&rcur[rl], 1);
        sorted[dst] = make_float2(__uint_as_float(q.x), __int_as_float(c));
    }
    if (b == 0 && t == 0) rowptr[N_ROWS] = NNZ;
}

// ---------------------------------------------------------------------------
// fused layer: CSR SpMM with a SCALARIZED edge stream (wave-uniform s_loads,
// no shfl/bpermute) + perturb + acc update.
//   x(c)   = c  < USER_NUM ? xa[c] : xb[c-USER_NUM]    (layer>=1: both = cur)
//   src(r) = r  < USER_NUM ? sa[r] : sb[r-USER_NUM]    (layer>=1: both = acc)
// ---------------------------------------------------------------------------
__global__ __launch_bounds__(256) void layer_kernel(
    const float2* __restrict__ sorted, const int* __restrict__ rowptr,
    const float* __restrict__ xa, const float* __restrict__ xb,
    const float* __restrict__ sa, const float* __restrict__ sb,
    float* __restrict__ ego_out, const float* __restrict__ noise,
    float* __restrict__ acc_out, int last)
{
    int row = blockIdx.x * 4 + (threadIdx.x >> 6);
    if (row >= N_ROWS) return;
    int lane = threadIdx.x & 63;

    int s0  = __builtin_amdgcn_readfirstlane(rowptr[row]);
    int s1  = __builtin_amdgcn_readfirstlane(rowptr[row + 1]);
    int deg = s1 - s0;
    const float2* ep = sorted + s0;

    float accv = 0.f;
    int e = 0;
    for (; e + 8 <= deg; e += 8) {
        float2 q0 = ep[e + 0], q1 = ep[e + 1], q2 = ep[e + 2], q3 = ep[e + 3];
        float2 q4 = ep[e + 4], q5 = ep[e + 5], q6 = ep[e + 6], q7 = ep[e + 7];
        int c0 = __float_as_int(q0.y), c1 = __float_as_int(q1.y);
        int c2 = __float_as_int(q2.y), c3 = __float_as_int(q3.y);
        int c4 = __float_as_int(q4.y), c5 = __float_as_int(q5.y);
        int c6 = __float_as_int(q6.y), c7 = __float_as_int(q7.y);
        const float* p0 = (c0 < USER_NUM) ? xa + (size_t)c0 * EMB : xb + (size_t)(c0 - USER_NUM) * EMB;
        const float* p1 = (c1 < USER_NUM) ? xa + (size_t)c1 * EMB : xb + (size_t)(c1 - USER_NUM) * EMB;
        const float* p2 = (c2 < USER_NUM) ? xa + (size_t)c2 * EMB : xb + (size_t)(c2 - USER_NUM) * EMB;
        const float* p3 = (c3 < USER_NUM) ? xa + (size_t)c3 * EMB : xb + (size_t)(c3 - USER_NUM) * EMB;
        const float* p4 = (c4 < USER_NUM) ? xa + (size_t)c4 * EMB : xb + (size_t)(c4 - USER_NUM) * EMB;
        const float* p5 = (c5 < USER_NUM) ? xa + (size_t)c5 * EMB : xb + (size_t)(c5 - USER_NUM) * EMB;
        const float* p6 = (c6 < USER_NUM) ? xa + (size_t)c6 * EMB : xb + (size_t)(c6 - USER_NUM) * EMB;
        const float* p7 = (c7 < USER_NUM) ? xa + (size_t)c7 * EMB : xb + (size_t)(c7 - USER_NUM) * EMB;
        float x0 = p0[lane], x1 = p1[lane], x2 = p2[lane], x3 = p3[lane];
        float x4 = p4[lane], x5 = p5[lane], x6 = p6[lane], x7 = p7[lane];
        accv = fmaf(q0.x, x0, accv);
        accv = fmaf(q1.x, x1, accv);
        accv = fmaf(q2.x, x2, accv);
        accv = fmaf(q3.x, x3, accv);
        accv = fmaf(q4.x, x4, accv);
        accv = fmaf(q5.x, x5, accv);
        accv = fmaf(q6.x, x6, accv);
        accv = fmaf(q7.x, x7, accv);
    }
    for (; e < deg; ++e) {
        float2 q = ep[e];
        int c = __float_as_int(q.y);
        const float* p = (c < USER_NUM) ? xa + (size_t)c * EMB : xb + (size_t)(c - USER_NUM) * EMB;
        accv = fmaf(q.x, p[lane], accv);
    }

    int idx = row * EMB + lane;
    float nv = __builtin_nontemporal_load(&noise[idx]);
    float s = nv * nv;
    #pragma unroll
    for (int off = 32; off; off >>= 1) s += __shfl_xor(s, off, 64);
    float nrm = nv / fmaxf(sqrtf(s), 1e-12f);

    float sg = (accv > 0.f) ? 1.f : ((accv < 0.f) ? -1.f : 0.f);
    float e2 = accv + sg * nrm * EPS;

    const float* srow = (row < USER_NUM) ? sa + (size_t)row * EMB
                                         : sb + (size_t)(row - USER_NUM) * EMB;
    float a = srow[lane] + e2;
    if (last) {
        __builtin_nontemporal_store(a * 0.25f, &acc_out[idx]);  // /(N_LAYERS+1)
    } else {
        acc_out[idx] = a;
        ego_out[idx] = e2;           // next layer's input
    }
}

// ---------------------------------------------------------------------------
// fallback path (atomic SpMM) if ws_size is too small for the sort
// ---------------------------------------------------------------------------
__global__ __launch_bounds__(256) void spmm_atomic_kernel(
    const float* __restrict__ vals, const int* __restrict__ rows,
    const int* __restrict__ cols, const float* __restrict__ x,
    float* __restrict__ y)
{
    int e = blockIdx.x * 4 + (threadIdx.x >> 6);
    if (e >= NNZ) return;
    int d = threadIdx.x & 63;
    atomicAdd(&y[(size_t)rows[e] * EMB + d], vals[e] * x[(size_t)cols[e] * EMB + d]);
}

__global__ __launch_bounds__(256) void perturb_atomic_kernel(
    float* __restrict__ ego, const float* __restrict__ noise,
    float* __restrict__ acc, float* __restrict__ zero_buf, int last)
{
    int row = blockIdx.x * 4 + (threadIdx.x >> 6);
    if (row >= N_ROWS) return;
    int d = threadIdx.x & 63;
    int idx = row * EMB + d;
    float nv = noise[idx];
    float s = nv * nv;
    #pragma unroll
    for (int off = 32; off; off >>= 1) s += __shfl_xor(s, off, 64);
    float nrm = nv / fmaxf(sqrtf(s), 1e-12f);
    float e = ego[idx];
    float sg = (e > 0.f) ? 1.f : ((e < 0.f) ? -1.f : 0.f);
    float e2 = e + sg * nrm * EPS;
    float a = acc[idx] + e2;
    if (last) acc[idx] = a * 0.25f;
    else { acc[idx] = a; ego[idx] = e2; zero_buf[idx] = 0.f; }
}

// ---------------------------------------------------------------------------
extern "C" void kernel_launch(void* const* d_in, const int* in_sizes, int n_in,
                              void* d_out, int out_size, void* d_ws, size_t ws_size,
                              hipStream_t stream)
{
    const float* user  = (const float*)d_in[0];
    const float* item  = (const float*)d_in[1];
    const float* vals  = (const float*)d_in[2];
    const float* noise = (const float*)d_in[3];
    const int*   rows  = (const int*)d_in[4];
    const int*   cols  = (const int*)d_in[5];
    float* out = (float*)d_out;

    const size_t nelem = (size_t)N_ROWS * EMB;

    // workspace layout
    float*  bufA    = (float*)d_ws;                      // N*EMB
    float*  bufB    = bufA + nelem;                      // N*EMB
    float2* sorted  = (float2*)(bufB + nelem);           // NNZ float2
    int*    rowptr  = (int*)(sorted + NNZ);              // N_ROWS + 1
    int*    gbcnt   = rowptr + (N_ROWS + 1);             // NBP
    int*    gbstart = gbcnt + NBP;                       // NBP
    int*    gcur    = gbstart + NBP;                     // NBP
    uint2*  p1out   = (uint2*)bufB;                      // overlays bufB (dead until layer0 output)

    const size_t need = (2 * nelem + 2 * NNZ) * 4 + (N_ROWS + 1 + 3 * NBP) * 4;
    const int row_blocks = (N_ROWS + 3) / 4;
    const int total4 = N_ROWS * EMB / 4;

    if (ws_size >= need) {
        // ---- sorted CSR path ----
        hipMemsetAsync(gbcnt, 0, NBP * sizeof(int), stream);
        bucket_count_kernel<<<P1_BLOCKS, 256, 0, stream>>>(rows, gbcnt);
        bucket_scan_kernel<<<1, NBP, 0, stream>>>(gbcnt, gbstart, gcur);
        pass1_kernel<<<P1_BLOCKS, P1_T, 0, stream>>>(rows, cols, vals, gcur, p1out);
        pass2_kernel<<<NBUCK, NBP, 0, stream>>>(p1out, gbcnt, gbstart, rowptr, sorted);

        // layer 0: gather straight from user/item (no init/copy); acc source
        // is the concat row itself. Output ego1 -> bufB (overwrites p1out).
        layer_kernel<<<row_blocks, 256, 0, stream>>>(
            sorted, rowptr, user, item, user, item,
            bufB, noise, out, 0);
        // layer 1: x = bufB, src = out(acc); ego2 -> bufA
        layer_kernel<<<row_blocks, 256, 0, stream>>>(
            sorted, rowptr, bufB, bufB + (size_t)USER_NUM * EMB,
            out, out + (size_t)USER_NUM * EMB,
            bufA, noise + nelem, out, 0);
        // layer 2 (last): x = bufA; writes averaged acc only
        layer_kernel<<<row_blocks, 256, 0, stream>>>(
            sorted, rowptr, bufA, bufA + (size_t)USER_NUM * EMB,
            out, out + (size_t)USER_NUM * EMB,
            nullptr, noise + 2 * nelem, out, 1);
    } else {
        // ---- fallback: atomic SpMM path ----
        hipMemsetAsync(bufB, 0, nelem * sizeof(float), stream);
        init_kernel<<<(total4 + 255) / 256, 256, 0, stream>>>(user, item, bufA, out);
        float* cur = bufA;
        float* nxt = bufB;
        const int spmm_blocks = (NNZ + 3) / 4;
        for (int k = 0; k < N_LAYERS; ++k) {
            spmm_atomic_kernel<<<spmm_blocks, 256, 0, stream>>>(vals, rows, cols, cur, nxt);
            int last = (k == N_LAYERS - 1);
            perturb_atomic_kernel<<<row_blocks, 256, 0, stream>>>(
                nxt, noise + (size_t)k * nelem, out, cur, last);
            float* t = cur; cur = nxt; nxt = t;
        }
    }
}